// Round 10
// baseline (1055.371 us; speedup 1.0000x reference)
//
#include <hip/hip_runtime.h>

#define NN 100000
#define NE 1600000
#define DF 128
#define DOUT 64
#define NG 128
#define NB 391      // ceil(NN/256) buckets of 256 nodes
#define EPB 8192    // edges per block in binning passes
#define NBLKA ((NE + EPB - 1) / EPB)  // 196
#define PCH 8       // pool chunks per graph

typedef short short8 __attribute__((ext_vector_type(8)));
typedef float floatx4 __attribute__((ext_vector_type(4)));
typedef unsigned int uintx2 __attribute__((ext_vector_type(2)));

__device__ __forceinline__ unsigned short f2bf(float f) {
    unsigned int b = __float_as_uint(f);
    unsigned int r = (b + 0x7fffu + ((b >> 16) & 1u)) >> 16;
    return (unsigned short)r;
}
__device__ __forceinline__ float bf2f_lo(unsigned int v) { return __uint_as_float(v << 16); }
__device__ __forceinline__ float bf2f_hi(unsigned int v) { return __uint_as_float(v & 0xffff0000u); }

// physical feature index p -> logical feature c.
// p = g*64 + lm*4 + u  (g:0..1, lm:0..15, u:0..3), c = (g*4+u)*16 + lm
__device__ __forceinline__ int phi(int p) {
    return (((p >> 6) << 2) + (p & 3)) * 16 + ((p >> 2) & 15);
}

// chunk-major addressing: physical feature p of row r lives at
// table[((p>>4)*NN + r)*16 + (p&15)]  (element size = table dtype)

// ---------------- CSR build: LDS-binned radix partition ----------------

__global__ void k_init(int* __restrict__ bhist, const int* __restrict__ batch,
                       int* __restrict__ gstart) {
    if (blockIdx.x < 2) {
        int i = blockIdx.x * 256 + threadIdx.x;
        if (i < NB) bhist[i] = 0;
    } else {
        int g = threadIdx.x;
        if (g > NG) return;
        int lo = 0, hi = NN;
        while (lo < hi) {
            int mid = (lo + hi) >> 1;
            if (batch[mid] < g) lo = mid + 1; else hi = mid;
        }
        gstart[g] = lo;
    }
}

__global__ __launch_bounds__(256) void k_bcount(const int* __restrict__ dst,
                                                int* __restrict__ bhist) {
    __shared__ int lh[NB];
    int t = threadIdx.x;
    for (int i = t; i < NB; i += 256) lh[i] = 0;
    __syncthreads();
    int e0 = blockIdx.x * EPB;
    int e1 = min(e0 + EPB, NE);
    for (int e = e0 + t; e < e1; e += 256) atomicAdd(&lh[dst[e] >> 8], 1);
    __syncthreads();
    for (int i = t; i < NB; i += 256) {
        int c = lh[i];
        if (c) atomicAdd(&bhist[i], c);
    }
}

__global__ __launch_bounds__(512) void k_bscan(const int* __restrict__ bhist,
                                               int* __restrict__ bbase,
                                               int* __restrict__ bcur) {
    __shared__ int sh[512];
    int t = threadIdx.x;
    int v = (t < NB) ? bhist[t] : 0;
    sh[t] = v;
    __syncthreads();
    for (int off = 1; off < 512; off <<= 1) {
        int a = (t >= off) ? sh[t - off] : 0;
        __syncthreads();
        sh[t] += a;
        __syncthreads();
    }
    if (t < NB) {
        bbase[t] = sh[t] - v;
        bcur[t] = sh[t] - v;
    }
    if (t == NB - 1) bbase[NB] = sh[t];
}

__global__ __launch_bounds__(256) void k_pairs(const int* __restrict__ src,
                                               const int* __restrict__ dst,
                                               int* __restrict__ bcur,
                                               int2* __restrict__ ebuf) {
    __shared__ int lh[NB];
    __shared__ int lbase[NB];
    int t = threadIdx.x;
    for (int i = t; i < NB; i += 256) lh[i] = 0;
    __syncthreads();
    int e0 = blockIdx.x * EPB;
    int e1 = min(e0 + EPB, NE);
    for (int e = e0 + t; e < e1; e += 256) atomicAdd(&lh[dst[e] >> 8], 1);
    __syncthreads();
    for (int i = t; i < NB; i += 256) {
        int c = lh[i];
        lbase[i] = c ? atomicAdd(&bcur[i], c) : 0;
    }
    __syncthreads();
    for (int i = t; i < NB; i += 256) lh[i] = 0;
    __syncthreads();
    for (int e = e0 + t; e < e1; e += 256) {
        int s = src[e], d = dst[e];
        int bk = d >> 8;
        int off = atomicAdd(&lh[bk], 1);
        ebuf[lbase[bk] + off] = make_int2(s, d);
    }
}

__global__ __launch_bounds__(256) void k_build(const int2* __restrict__ ebuf,
                                               const int* __restrict__ bbase,
                                               int* __restrict__ rowptr,
                                               float* __restrict__ dinv,
                                               int* __restrict__ col) {
    __shared__ int deg[256];
    __shared__ int lst[256];
    int b = blockIdx.x, t = threadIdx.x;
    int n0 = b << 8;
    int node = n0 + t;
    deg[t] = 0;
    __syncthreads();
    int e0 = bbase[b], e1 = bbase[b + 1];
    for (int e = e0 + t; e < e1; e += 256) atomicAdd(&deg[ebuf[e].y - n0], 1);
    __syncthreads();
    int v = deg[t];
    lst[t] = v;
    __syncthreads();
    for (int off = 1; off < 256; off <<= 1) {
        int a = (t >= off) ? lst[t - off] : 0;
        __syncthreads();
        lst[t] += a;
        __syncthreads();
    }
    int mystart = e0 + lst[t] - v;
    if (node < NN) {
        rowptr[node] = mystart;
        dinv[node] = rsqrtf((float)(v + 1));  // +1 self-loop
    }
    if (b == NB - 1 && t == 255) rowptr[NN] = e1;
    lst[t] = mystart;
    __syncthreads();
    for (int e = e0 + t; e < e1; e += 256) {
        int2 pr = ebuf[e];
        int p = atomicAdd(&lst[pr.y - n0], 1);
        col[p] = pr.x;
    }
}

// ---------------- bf16 conversions ----------------

__global__ __launch_bounds__(256) void k_prepw(const float* __restrict__ Wa,
                                               const float* __restrict__ Wbm,
                                               const float* __restrict__ Wc,
                                               unsigned short* __restrict__ Oa,
                                               unsigned short* __restrict__ Ob,
                                               unsigned short* __restrict__ Oc) {
    const float* W = (blockIdx.y == 0) ? Wa : (blockIdx.y == 1) ? Wbm : Wc;
    unsigned short* O = (blockIdx.y == 0) ? Oa : (blockIdx.y == 1) ? Ob : Oc;
    int idx = blockIdx.x * 256 + threadIdx.x;
    if (idx >= 2048) return;
    int l = idx & 63;
    int s = (idx >> 6) & 3;
    int t = idx >> 8;
    int k0 = s * 32 + (l >> 4) * 8;
    int c = t * 16 + (l & 15);
    unsigned short o[8];
#pragma unroll
    for (int j = 0; j < 8; j++) o[j] = f2bf(W[phi(k0 + j) * DF + c]);
    *(short8*)&O[idx * 8] = *(short8*)o;
}

// x f32 -> bf16, permuted feature order, chunk-major storage
__global__ __launch_bounds__(256) void k_prepx(const float* __restrict__ x,
                                               unsigned short* __restrict__ xc) {
    size_t i = ((size_t)blockIdx.x * 256 + threadIdx.x) * 8;
    if (i >= (size_t)NN * DF) return;
    size_t row = i >> 7;
    int p0 = (int)(i & 127);  // multiple of 8
    unsigned short o[8];
#pragma unroll
    for (int j = 0; j < 8; j++) o[j] = f2bf(x[(row << 7) + phi(p0 + j)]);
    *(short8*)&xc[((size_t)(p0 >> 4) * NN + row) * 16 + (p0 & 15)] = *(short8*)o;
}

// ---------------- per-layer compute ----------------

__global__ __launch_bounds__(256) void k_gemm(const unsigned short* __restrict__ X,
                                              const unsigned short* __restrict__ Wb,
                                              const float* __restrict__ dinv,
                                              unsigned short* __restrict__ hsc,
                                              unsigned char* __restrict__ fs8c) {
    int t = threadIdx.x;
    int wave = t >> 6, l = t & 63;
    int r0 = blockIdx.x * 64 + wave * 16;
    int lm = l & 15, q = l >> 4;

    int arow = r0 + lm;
    if (arow >= NN) arow = NN - 1;
    // chunk-major A-fragment reads: feats [q*8+32*i, +8) -> chunk (q>>1)+2i, off (q&1)*8
    int offq = (q & 1) * 8;
    int chq = q >> 1;
    short8 af0 = *(const short8*)&X[((size_t)(chq + 0) * NN + arow) * 16 + offq];
    short8 af1 = *(const short8*)&X[((size_t)(chq + 2) * NN + arow) * 16 + offq];
    short8 af2 = *(const short8*)&X[((size_t)(chq + 4) * NN + arow) * 16 + offq];
    short8 af3 = *(const short8*)&X[((size_t)(chq + 6) * NN + arow) * 16 + offq];

    int orow = r0 + q * 4;
    float dv[4];
#pragma unroll
    for (int j = 0; j < 4; j++) dv[j] = (orow + j < NN) ? dinv[orow + j] : 0.f;

    float res[4][8];
#pragma unroll
    for (int tt = 0; tt < 8; tt++) {
        floatx4 acc = {0.f, 0.f, 0.f, 0.f};
        const unsigned short* wp = Wb + ((size_t)(tt * 4) * 64 + l) * 8;
        acc = __builtin_amdgcn_mfma_f32_16x16x32_bf16(af0, *(const short8*)(wp), acc, 0, 0, 0);
        acc = __builtin_amdgcn_mfma_f32_16x16x32_bf16(af1, *(const short8*)(wp + 512), acc, 0, 0, 0);
        acc = __builtin_amdgcn_mfma_f32_16x16x32_bf16(af2, *(const short8*)(wp + 1024), acc, 0, 0, 0);
        acc = __builtin_amdgcn_mfma_f32_16x16x32_bf16(af3, *(const short8*)(wp + 1536), acc, 0, 0, 0);
#pragma unroll
        for (int j = 0; j < 4; j++) res[j][tt] = acc[j] * dv[j];
    }

    // epilogue: physical p = g*64 + lm*4 + u -> chunk g*4+(lm>>2), off (lm&3)*4+u
#pragma unroll
    for (int g = 0; g < 2; g++) {
        int ch = g * 4 + (lm >> 2);
        int off = (lm & 3) * 4;
#pragma unroll
        for (int j = 0; j < 4; j++) {
            int r = orow + j;
            if (r >= NN) continue;
            float v0 = res[j][g * 4 + 0], v1 = res[j][g * 4 + 1];
            float v2 = res[j][g * 4 + 2], v3 = res[j][g * 4 + 3];
            uintx2 bfp;
            bfp.x = (unsigned int)f2bf(v0) | ((unsigned int)f2bf(v1) << 16);
            bfp.y = (unsigned int)f2bf(v2) | ((unsigned int)f2bf(v3) << 16);
            size_t base = ((size_t)ch * NN + r) * 16 + off;
            *(uintx2*)&hsc[base] = bfp;
            unsigned int w8 = __builtin_amdgcn_cvt_pk_fp8_f32(v0, v1, 0, false);
            w8 = __builtin_amdgcn_cvt_pk_fp8_f32(v2, v3, w8, true);
            *(unsigned int*)&fs8c[base] = w8;
        }
    }
}

// chunk-parallel aggregate: block handles chunk ch = blockIdx&7 (XCD-pinned under
// round-robin dispatch -> 1.6MB chunk table L2-resident). 1 wave = 1 node;
// lane = (e 0..15, qu 0..3): 16 edges x 4 feats per iteration.
__global__ __launch_bounds__(256) void k_agg(const unsigned short* __restrict__ hsc,
                                             const unsigned char* __restrict__ fs8c,
                                             const int* __restrict__ rowptr,
                                             const int* __restrict__ col,
                                             const float* __restrict__ dinv,
                                             const float* __restrict__ b,
                                             unsigned short* __restrict__ outc) {
    int ch = blockIdx.x & 7;
    int n = ((blockIdx.x >> 3) << 2) + (threadIdx.x >> 6);
    int lane = threadIdx.x & 63;
    int e = lane >> 2;
    int qu = lane & 3;
    const unsigned char* tbl = fs8c + (size_t)ch * NN * 16;

    int e0 = rowptr[n], e1 = rowptr[n + 1];
    float a0 = 0.f, a1 = 0.f, a2 = 0.f, a3 = 0.f;
    for (int base = e0; base < e1; base += 16) {
        int idx = base + e;
        int cs = __builtin_nontemporal_load(&col[min(idx, e1 - 1)]);
        unsigned int v = *(const unsigned int*)&tbl[(size_t)cs * 16 + qu * 4];
        if (idx < e1) {
            a0 += __builtin_amdgcn_cvt_f32_fp8(v, 0);
            a1 += __builtin_amdgcn_cvt_f32_fp8(v, 1);
            a2 += __builtin_amdgcn_cvt_f32_fp8(v, 2);
            a3 += __builtin_amdgcn_cvt_f32_fp8(v, 3);
        }
    }
#pragma unroll
    for (int off = 4; off < 64; off <<= 1) {
        a0 += __shfl_xor(a0, off);
        a1 += __shfl_xor(a1, off);
        a2 += __shfl_xor(a2, off);
        a3 += __shfl_xor(a3, off);
    }

    if (e == 0) {  // lanes 0..3, qu = lane
        size_t base = ((size_t)ch * NN + n) * 16 + qu * 4;
        uintx2 sv = __builtin_nontemporal_load((const uintx2*)&hsc[base]);
        float dvn = dinv[n];
        int p = ch * 16 + qu * 4;
        float o0 = fmaxf(dvn * (a0 + bf2f_lo(sv.x)) + b[phi(p + 0)], 0.f);
        float o1 = fmaxf(dvn * (a1 + bf2f_hi(sv.x)) + b[phi(p + 1)], 0.f);
        float o2 = fmaxf(dvn * (a2 + bf2f_lo(sv.y)) + b[phi(p + 2)], 0.f);
        float o3 = fmaxf(dvn * (a3 + bf2f_hi(sv.y)) + b[phi(p + 3)], 0.f);
        uintx2 pk;
        pk.x = (unsigned int)f2bf(o0) | ((unsigned int)f2bf(o1) << 16);
        pk.y = (unsigned int)f2bf(o2) | ((unsigned int)f2bf(o3) << 16);
        __builtin_nontemporal_store(pk, (uintx2*)&outc[base]);
    }
}

// ---------------- pooling + FC ----------------

__global__ __launch_bounds__(256) void k_poolA(const unsigned short* __restrict__ h,
                                               const int* __restrict__ gstart,
                                               float* __restrict__ part) {
    __shared__ float2 red[256];
    int g = blockIdx.x >> 3, c = blockIdx.x & 7;
    int s = gstart[g], e = gstart[g + 1];
    int len = e - s;
    int cs = s + (int)(((long long)len * c) >> 3);
    int ce = s + (int)(((long long)len * (c + 1)) >> 3);
    int t = threadIdx.x;
    int fp = t & 63;   // physical feature pair: feats fp*2, fp*2+1
    int rs = t >> 6;
    size_t chbase = (size_t)(fp >> 3) * NN * 16;
    int off = (fp & 7) * 2;
    float2 acc = make_float2(0.f, 0.f);
    for (int n = cs + rs; n < ce; n += 4) {
        unsigned int v = *(const unsigned int*)&h[chbase + (size_t)n * 16 + off];
        acc.x += bf2f_lo(v);
        acc.y += bf2f_hi(v);
    }
    red[t] = acc;
    __syncthreads();
    if (rs == 0) {
        float2 a0 = red[fp], a1 = red[fp + 64], a2 = red[fp + 128], a3 = red[fp + 192];
        float2 o;
        o.x = (a0.x + a1.x) + (a2.x + a3.x);
        o.y = (a0.y + a1.y) + (a2.y + a3.y);
        *(float2*)&part[(size_t)blockIdx.x * DF + fp * 2] = o;
    }
}

__global__ __launch_bounds__(128) void k_poolB(const float* __restrict__ part,
                                               const int* __restrict__ gstart,
                                               float* __restrict__ pooled) {
    int g = blockIdx.x;
    int f = threadIdx.x;
    float s = 0.f;
#pragma unroll
    for (int c = 0; c < PCH; c++) s += part[(size_t)(g * PCH + c) * DF + f];
    int cnt = gstart[g + 1] - gstart[g];
    pooled[g * DF + phi(f)] = s / (float)max(cnt, 1);
}

__global__ __launch_bounds__(64) void k_fc(const float* __restrict__ pooled,
                                           const float* __restrict__ Wfc,
                                           const float* __restrict__ bfc,
                                           float* __restrict__ out) {
    int g = blockIdx.x;
    int o = threadIdx.x;
    float acc = bfc[o];
    for (int k = 0; k < DF; k++) acc += pooled[g * DF + k] * Wfc[k * DOUT + o];
    out[g * DOUT + o] = acc;
}

// ---------------- launch ----------------

extern "C" void kernel_launch(void* const* d_in, const int* in_sizes, int n_in,
                              void* d_out, int out_size, void* d_ws, size_t ws_size,
                              hipStream_t stream) {
    const float* x     = (const float*)d_in[0];
    const int*   ei    = (const int*)d_in[1];
    const int*   batch = (const int*)d_in[2];
    const float* W1 = (const float*)d_in[3];
    const float* b1 = (const float*)d_in[4];
    const float* W2 = (const float*)d_in[5];
    const float* b2 = (const float*)d_in[6];
    const float* W3 = (const float*)d_in[7];
    const float* b3 = (const float*)d_in[8];
    const float* Wfc = (const float*)d_in[9];
    const float* bfc = (const float*)d_in[10];
    float* out = (float*)d_out;

    char* p = (char*)d_ws;
    unsigned short* xc = (unsigned short*)p;  p += (size_t)NN * DF * sizeof(short);
    unsigned short* hsc = (unsigned short*)p; p += (size_t)NN * DF * sizeof(short);
    unsigned short* obc = (unsigned short*)p; p += (size_t)NN * DF * sizeof(short);
    unsigned char*  fs8c = (unsigned char*)p; p += (size_t)NN * DF;
    unsigned short* Wb1 = (unsigned short*)p; p += 16384 * sizeof(short);
    unsigned short* Wb2 = (unsigned short*)p; p += 16384 * sizeof(short);
    unsigned short* Wb3 = (unsigned short*)p; p += 16384 * sizeof(short);
    float* dinv = (float*)p;           p += (size_t)NN * sizeof(float);
    int* rowptr = (int*)p;             p += (size_t)(NN + 4) * sizeof(int);
    int* col    = (int*)p;             p += (size_t)NE * sizeof(int);
    int2* ebuf  = (int2*)p;            p += (size_t)NE * sizeof(int2);
    int* bhist  = (int*)p;             p += (size_t)(NB + 4) * sizeof(int);
    int* bbase  = (int*)p;             p += (size_t)(NB + 4) * sizeof(int);
    int* bcur   = (int*)p;             p += (size_t)(NB + 4) * sizeof(int);
    int* gstart = (int*)p;             p += (size_t)(NG + 4) * sizeof(int);
    float* pooled = (float*)p;         p += (size_t)NG * DF * sizeof(float);
    float* part  = (float*)p;          p += (size_t)NG * PCH * DF * sizeof(float);

    const int* e_src = ei;
    const int* e_dst = ei + NE;

    // CSR build + graph bounds
    k_init<<<3, 256, 0, stream>>>(bhist, batch, gstart);
    k_bcount<<<NBLKA, 256, 0, stream>>>(e_dst, bhist);
    k_bscan<<<1, 512, 0, stream>>>(bhist, bbase, bcur);
    k_pairs<<<NBLKA, 256, 0, stream>>>(e_src, e_dst, bcur, ebuf);
    k_build<<<NB, 256, 0, stream>>>(ebuf, bbase, rowptr, dinv, col);

    // bf16 conversions
    k_prepw<<<dim3(8, 3), 256, 0, stream>>>(W1, W2, W3, Wb1, Wb2, Wb3);
    k_prepx<<<(NN * DF / 8 + 255) / 256, 256, 0, stream>>>(x, xc);

    int ggrid = (NN + 63) / 64;
    int agg_blocks = (NN / 4) * 8;   // 4 nodes/block x 8 chunks

    // layer 1
    k_gemm<<<ggrid, 256, 0, stream>>>(xc, Wb1, dinv, hsc, fs8c);
    k_agg<<<agg_blocks, 256, 0, stream>>>(hsc, fs8c, rowptr, col, dinv, b1, obc);
    // layer 2
    k_gemm<<<ggrid, 256, 0, stream>>>(obc, Wb2, dinv, hsc, fs8c);
    k_agg<<<agg_blocks, 256, 0, stream>>>(hsc, fs8c, rowptr, col, dinv, b2, obc);
    // layer 3
    k_gemm<<<ggrid, 256, 0, stream>>>(obc, Wb3, dinv, hsc, fs8c);
    k_agg<<<agg_blocks, 256, 0, stream>>>(hsc, fs8c, rowptr, col, dinv, b3, obc);

    // pool + fc
    k_poolA<<<NG * PCH, 256, 0, stream>>>(obc, gstart, part);
    k_poolB<<<NG, 128, 0, stream>>>(part, gstart, pooled);
    k_fc<<<NG, 64, 0, stream>>>(pooled, Wfc, bfc, out);
}

// Round 12
// 390.094 us; speedup vs baseline: 2.7054x; 2.7054x over previous
//
#include <hip/hip_runtime.h>

#define NN 100000
#define NE 1600000
#define DF 128
#define DOUT 64
#define NG 128
#define NB 391      // ceil(NN/256) buckets of 256 nodes
#define EPB 8192    // edges per block in binning passes
#define NBLKA ((NE + EPB - 1) / EPB)  // 196
#define PCH 8       // pool chunks per graph

typedef short short8 __attribute__((ext_vector_type(8)));
typedef float floatx4 __attribute__((ext_vector_type(4)));

__device__ __forceinline__ unsigned short f2bf(float f) {
    unsigned int b = __float_as_uint(f);
    unsigned int r = (b + 0x7fffu + ((b >> 16) & 1u)) >> 16;
    return (unsigned short)r;
}
__device__ __forceinline__ float bf2f_lo(unsigned int v) { return __uint_as_float(v << 16); }
__device__ __forceinline__ float bf2f_hi(unsigned int v) { return __uint_as_float(v & 0xffff0000u); }

// fp8 byte-selector must be a literal: explicit helpers
__device__ __forceinline__ void acc_fp8x4(float* a, unsigned int v) {
    a[0] += __builtin_amdgcn_cvt_f32_fp8(v, 0);
    a[1] += __builtin_amdgcn_cvt_f32_fp8(v, 1);
    a[2] += __builtin_amdgcn_cvt_f32_fp8(v, 2);
    a[3] += __builtin_amdgcn_cvt_f32_fp8(v, 3);
}
__device__ __forceinline__ void unp_fp8x4(unsigned int v, float* o) {
    o[0] = __builtin_amdgcn_cvt_f32_fp8(v, 0);
    o[1] = __builtin_amdgcn_cvt_f32_fp8(v, 1);
    o[2] = __builtin_amdgcn_cvt_f32_fp8(v, 2);
    o[3] = __builtin_amdgcn_cvt_f32_fp8(v, 3);
}

// physical feature index p -> logical feature c.
// p = g*64 + lm*4 + u  (g:0..1, lm:0..15, u:0..3), c = (g*4+u)*16 + lm
__device__ __forceinline__ int phi(int p) {
    return (((p >> 6) << 2) + (p & 3)) * 16 + ((p >> 2) & 15);
}

// ---------------- CSR build: LDS-binned radix partition ----------------

__global__ void k_init(int* __restrict__ bhist, const int* __restrict__ batch,
                       int* __restrict__ gstart) {
    if (blockIdx.x < 2) {
        int i = blockIdx.x * 256 + threadIdx.x;
        if (i < NB) bhist[i] = 0;
    } else {
        int g = threadIdx.x;
        if (g > NG) return;
        int lo = 0, hi = NN;
        while (lo < hi) {
            int mid = (lo + hi) >> 1;
            if (batch[mid] < g) lo = mid + 1; else hi = mid;
        }
        gstart[g] = lo;
    }
}

__global__ __launch_bounds__(256) void k_bcount(const int* __restrict__ dst,
                                                int* __restrict__ bhist) {
    __shared__ int lh[NB];
    int t = threadIdx.x;
    for (int i = t; i < NB; i += 256) lh[i] = 0;
    __syncthreads();
    int e0 = blockIdx.x * EPB;
    int e1 = min(e0 + EPB, NE);
    for (int e = e0 + t; e < e1; e += 256) atomicAdd(&lh[dst[e] >> 8], 1);
    __syncthreads();
    for (int i = t; i < NB; i += 256) {
        int c = lh[i];
        if (c) atomicAdd(&bhist[i], c);
    }
}

__global__ __launch_bounds__(512) void k_bscan(const int* __restrict__ bhist,
                                               int* __restrict__ bbase,
                                               int* __restrict__ bcur) {
    __shared__ int sh[512];
    int t = threadIdx.x;
    int v = (t < NB) ? bhist[t] : 0;
    sh[t] = v;
    __syncthreads();
    for (int off = 1; off < 512; off <<= 1) {
        int a = (t >= off) ? sh[t - off] : 0;
        __syncthreads();
        sh[t] += a;
        __syncthreads();
    }
    if (t < NB) {
        bbase[t] = sh[t] - v;
        bcur[t] = sh[t] - v;
    }
    if (t == NB - 1) bbase[NB] = sh[t];
}

__global__ __launch_bounds__(256) void k_pairs(const int* __restrict__ src,
                                               const int* __restrict__ dst,
                                               int* __restrict__ bcur,
                                               int2* __restrict__ ebuf) {
    __shared__ int lh[NB];
    __shared__ int lbase[NB];
    int t = threadIdx.x;
    for (int i = t; i < NB; i += 256) lh[i] = 0;
    __syncthreads();
    int e0 = blockIdx.x * EPB;
    int e1 = min(e0 + EPB, NE);
    for (int e = e0 + t; e < e1; e += 256) atomicAdd(&lh[dst[e] >> 8], 1);
    __syncthreads();
    for (int i = t; i < NB; i += 256) {
        int c = lh[i];
        lbase[i] = c ? atomicAdd(&bcur[i], c) : 0;
    }
    __syncthreads();
    for (int i = t; i < NB; i += 256) lh[i] = 0;
    __syncthreads();
    for (int e = e0 + t; e < e1; e += 256) {
        int s = src[e], d = dst[e];
        int bk = d >> 8;
        int off = atomicAdd(&lh[bk], 1);
        ebuf[lbase[bk] + off] = make_int2(s, d);
    }
}

__global__ __launch_bounds__(256) void k_build(const int2* __restrict__ ebuf,
                                               const int* __restrict__ bbase,
                                               int* __restrict__ rowptr,
                                               float* __restrict__ dinv,
                                               int* __restrict__ col) {
    __shared__ int deg[256];
    __shared__ int lst[256];
    int b = blockIdx.x, t = threadIdx.x;
    int n0 = b << 8;
    int node = n0 + t;
    deg[t] = 0;
    __syncthreads();
    int e0 = bbase[b], e1 = bbase[b + 1];
    for (int e = e0 + t; e < e1; e += 256) atomicAdd(&deg[ebuf[e].y - n0], 1);
    __syncthreads();
    int v = deg[t];
    lst[t] = v;
    __syncthreads();
    for (int off = 1; off < 256; off <<= 1) {
        int a = (t >= off) ? lst[t - off] : 0;
        __syncthreads();
        lst[t] += a;
        __syncthreads();
    }
    int mystart = e0 + lst[t] - v;
    if (node < NN) {
        rowptr[node] = mystart;
        dinv[node] = rsqrtf((float)(v + 1));  // +1 self-loop
    }
    if (b == NB - 1 && t == 255) rowptr[NN] = e1;
    lst[t] = mystart;
    __syncthreads();
    for (int e = e0 + t; e < e1; e += 256) {
        int2 pr = ebuf[e];
        int p = atomicAdd(&lst[pr.y - n0], 1);
        col[p] = pr.x;
    }
}

// ---------------- bf16 conversions ----------------

__global__ __launch_bounds__(256) void k_prepw(const float* __restrict__ Wa,
                                               const float* __restrict__ Wbm,
                                               const float* __restrict__ Wc,
                                               unsigned short* __restrict__ Oa,
                                               unsigned short* __restrict__ Ob,
                                               unsigned short* __restrict__ Oc) {
    const float* W = (blockIdx.y == 0) ? Wa : (blockIdx.y == 1) ? Wbm : Wc;
    unsigned short* O = (blockIdx.y == 0) ? Oa : (blockIdx.y == 1) ? Ob : Oc;
    int idx = blockIdx.x * 256 + threadIdx.x;
    if (idx >= 2048) return;
    int l = idx & 63;
    int s = (idx >> 6) & 3;
    int t = idx >> 8;
    int k0 = s * 32 + (l >> 4) * 8;
    int c = t * 16 + (l & 15);
    unsigned short o[8];
#pragma unroll
    for (int j = 0; j < 8; j++) o[j] = f2bf(W[phi(k0 + j) * DF + c]);
    *(short8*)&O[idx * 8] = *(short8*)o;
}

// x f32 -> bf16, permuted feature order (row-major)
__global__ __launch_bounds__(256) void k_prepx(const float* __restrict__ x,
                                               unsigned short* __restrict__ xb) {
    size_t i = ((size_t)blockIdx.x * 256 + threadIdx.x) * 8;
    if (i >= (size_t)NN * DF) return;
    size_t rb = i & ~(size_t)127;
    int p0 = (int)(i & 127);
    unsigned short o[8];
#pragma unroll
    for (int j = 0; j < 8; j++) o[j] = f2bf(x[rb + phi(p0 + j)]);
    *(short8*)&xb[i] = *(short8*)o;
}

// ---------------- per-layer compute ----------------

// output ONLY fp8 (row-major, 128 B/row) — self term also read from fs8 in k_agg
__global__ __launch_bounds__(256) void k_gemm(const unsigned short* __restrict__ X,
                                              const unsigned short* __restrict__ Wb,
                                              const float* __restrict__ dinv,
                                              unsigned char* __restrict__ fs8) {
    int t = threadIdx.x;
    int wave = t >> 6, l = t & 63;
    int r0 = blockIdx.x * 64 + wave * 16;
    int lm = l & 15, q = l >> 4;

    int arow = r0 + lm;
    if (arow >= NN) arow = NN - 1;
    const unsigned short* xrow = X + (size_t)arow * DF + q * 8;
    short8 af0 = *(const short8*)(xrow);
    short8 af1 = *(const short8*)(xrow + 32);
    short8 af2 = *(const short8*)(xrow + 64);
    short8 af3 = *(const short8*)(xrow + 96);

    int orow = r0 + q * 4;
    float dv[4];
#pragma unroll
    for (int j = 0; j < 4; j++) dv[j] = (orow + j < NN) ? dinv[orow + j] : 0.f;

    float res[4][8];
#pragma unroll
    for (int tt = 0; tt < 8; tt++) {
        floatx4 acc = {0.f, 0.f, 0.f, 0.f};
        const unsigned short* wp = Wb + ((size_t)(tt * 4) * 64 + l) * 8;
        acc = __builtin_amdgcn_mfma_f32_16x16x32_bf16(af0, *(const short8*)(wp), acc, 0, 0, 0);
        acc = __builtin_amdgcn_mfma_f32_16x16x32_bf16(af1, *(const short8*)(wp + 512), acc, 0, 0, 0);
        acc = __builtin_amdgcn_mfma_f32_16x16x32_bf16(af2, *(const short8*)(wp + 1024), acc, 0, 0, 0);
        acc = __builtin_amdgcn_mfma_f32_16x16x32_bf16(af3, *(const short8*)(wp + 1536), acc, 0, 0, 0);
#pragma unroll
        for (int j = 0; j < 4; j++) res[j][tt] = acc[j] * dv[j];
    }

    // epilogue: physical p = g*64 + lm*4 holds logical cols (g*4+u)*16+lm
#pragma unroll
    for (int g = 0; g < 2; g++) {
#pragma unroll
        for (int j = 0; j < 4; j++) {
            int r = orow + j;
            if (r >= NN) continue;
            unsigned int w8 = __builtin_amdgcn_cvt_pk_fp8_f32(res[j][g * 4 + 0], res[j][g * 4 + 1], 0, false);
            w8 = __builtin_amdgcn_cvt_pk_fp8_f32(res[j][g * 4 + 2], res[j][g * 4 + 3], w8, true);
            *(unsigned int*)&fs8[(size_t)r * DF + g * 64 + lm * 4] = w8;
        }
    }
}

// 1 wave per node; lane = (sub 0..3, fo 0..15). 16 edges per iteration:
// 4 independent col loads then 4 independent 512B gathers in flight (2KB/wave MLP).
__global__ __launch_bounds__(256) void k_agg(const unsigned char* __restrict__ fs8,
                                             const int* __restrict__ rowptr,
                                             const int* __restrict__ col,
                                             const float* __restrict__ dinv,
                                             const float* __restrict__ b,
                                             unsigned short* __restrict__ out) {
    int n = (int)((blockIdx.x * (size_t)blockDim.x + threadIdx.x) >> 6);
    int lane = threadIdx.x & 63;
    int sub = lane >> 4;       // edge slot within group of 4
    int fo = lane & 15;        // feature octet: physical features fo*8..fo*8+7
    int foff = fo * 8;

    int e0 = rowptr[n], e1 = rowptr[n + 1];

    float accL[4] = {0.f, 0.f, 0.f, 0.f};
    float accH[4] = {0.f, 0.f, 0.f, 0.f};
    for (int base = e0; base < e1; base += 16) {
        int i0 = base + sub, i1 = base + 4 + sub, i2 = base + 8 + sub, i3 = base + 12 + sub;
        int c0 = col[min(i0, e1 - 1)];
        int c1 = col[min(i1, e1 - 1)];
        int c2 = col[min(i2, e1 - 1)];
        int c3 = col[min(i3, e1 - 1)];
        uint2 v0 = *(const uint2*)&fs8[(size_t)c0 * DF + foff];
        uint2 v1 = *(const uint2*)&fs8[(size_t)c1 * DF + foff];
        uint2 v2 = *(const uint2*)&fs8[(size_t)c2 * DF + foff];
        uint2 v3 = *(const uint2*)&fs8[(size_t)c3 * DF + foff];
        if (i0 < e1) { acc_fp8x4(accL, v0.x); acc_fp8x4(accH, v0.y); }
        if (i1 < e1) { acc_fp8x4(accL, v1.x); acc_fp8x4(accH, v1.y); }
        if (i2 < e1) { acc_fp8x4(accL, v2.x); acc_fp8x4(accH, v2.y); }
        if (i3 < e1) { acc_fp8x4(accL, v3.x); acc_fp8x4(accH, v3.y); }
    }
#pragma unroll
    for (int j = 0; j < 4; j++) {
        accL[j] += __shfl_xor(accL[j], 16);
        accL[j] += __shfl_xor(accL[j], 32);
        accH[j] += __shfl_xor(accH[j], 16);
        accH[j] += __shfl_xor(accH[j], 32);
    }

    if (sub == 0) {
        uint2 sv = *(const uint2*)&fs8[(size_t)n * DF + foff];  // self-loop row (fp8)
        float sL[4], sH[4];
        unp_fp8x4(sv.x, sL);
        unp_fp8x4(sv.y, sH);
        float dvn = dinv[n];
        float o[8];
#pragma unroll
        for (int j = 0; j < 4; j++)
            o[j] = fmaxf(dvn * (accL[j] + sL[j]) + b[phi(foff + j)], 0.f);
#pragma unroll
        for (int j = 0; j < 4; j++)
            o[4 + j] = fmaxf(dvn * (accH[j] + sH[j]) + b[phi(foff + 4 + j)], 0.f);
        uint4 pk;
        pk.x = (unsigned int)f2bf(o[0]) | ((unsigned int)f2bf(o[1]) << 16);
        pk.y = (unsigned int)f2bf(o[2]) | ((unsigned int)f2bf(o[3]) << 16);
        pk.z = (unsigned int)f2bf(o[4]) | ((unsigned int)f2bf(o[5]) << 16);
        pk.w = (unsigned int)f2bf(o[6]) | ((unsigned int)f2bf(o[7]) << 16);
        *(uint4*)&out[(size_t)n * DF + foff] = pk;
    }
}

// ---------------- pooling + FC ----------------

__global__ __launch_bounds__(256) void k_poolA(const unsigned short* __restrict__ h,
                                               const int* __restrict__ gstart,
                                               float* __restrict__ part) {
    __shared__ float2 red[256];
    int g = blockIdx.x >> 3, c = blockIdx.x & 7;
    int s = gstart[g], e = gstart[g + 1];
    int len = e - s;
    int cs = s + (int)(((long long)len * c) >> 3);
    int ce = s + (int)(((long long)len * (c + 1)) >> 3);
    int t = threadIdx.x;
    int fp = t & 63;
    int rs = t >> 6;
    float2 acc = make_float2(0.f, 0.f);
    for (int n = cs + rs; n < ce; n += 4) {
        unsigned int v = *(const unsigned int*)&h[(size_t)n * DF + fp * 2];
        acc.x += bf2f_lo(v);
        acc.y += bf2f_hi(v);
    }
    red[t] = acc;
    __syncthreads();
    if (rs == 0) {
        float2 a0 = red[fp], a1 = red[fp + 64], a2 = red[fp + 128], a3 = red[fp + 192];
        float2 o;
        o.x = (a0.x + a1.x) + (a2.x + a3.x);
        o.y = (a0.y + a1.y) + (a2.y + a3.y);
        *(float2*)&part[(size_t)blockIdx.x * DF + fp * 2] = o;
    }
}

__global__ __launch_bounds__(128) void k_poolB(const float* __restrict__ part,
                                               const int* __restrict__ gstart,
                                               float* __restrict__ pooled) {
    int g = blockIdx.x;
    int f = threadIdx.x;
    float s = 0.f;
#pragma unroll
    for (int c = 0; c < PCH; c++) s += part[(size_t)(g * PCH + c) * DF + f];
    int cnt = gstart[g + 1] - gstart[g];
    pooled[g * DF + phi(f)] = s / (float)max(cnt, 1);
}

__global__ __launch_bounds__(64) void k_fc(const float* __restrict__ pooled,
                                           const float* __restrict__ Wfc,
                                           const float* __restrict__ bfc,
                                           float* __restrict__ out) {
    int g = blockIdx.x;
    int o = threadIdx.x;
    float acc = bfc[o];
    for (int k = 0; k < DF; k++) acc += pooled[g * DF + k] * Wfc[k * DOUT + o];
    out[g * DOUT + o] = acc;
}

// ---------------- launch ----------------

extern "C" void kernel_launch(void* const* d_in, const int* in_sizes, int n_in,
                              void* d_out, int out_size, void* d_ws, size_t ws_size,
                              hipStream_t stream) {
    const float* x     = (const float*)d_in[0];
    const int*   ei    = (const int*)d_in[1];
    const int*   batch = (const int*)d_in[2];
    const float* W1 = (const float*)d_in[3];
    const float* b1 = (const float*)d_in[4];
    const float* W2 = (const float*)d_in[5];
    const float* b2 = (const float*)d_in[6];
    const float* W3 = (const float*)d_in[7];
    const float* b3 = (const float*)d_in[8];
    const float* Wfc = (const float*)d_in[9];
    const float* bfc = (const float*)d_in[10];
    float* out = (float*)d_out;

    char* p = (char*)d_ws;
    unsigned short* xb = (unsigned short*)p;  p += (size_t)NN * DF * sizeof(short);
    unsigned short* ob = (unsigned short*)p;  p += (size_t)NN * DF * sizeof(short);
    unsigned char*  fs8 = (unsigned char*)p;  p += (size_t)NN * DF;
    unsigned short* Wb1 = (unsigned short*)p; p += 16384 * sizeof(short);
    unsigned short* Wb2 = (unsigned short*)p; p += 16384 * sizeof(short);
    unsigned short* Wb3 = (unsigned short*)p; p += 16384 * sizeof(short);
    float* dinv = (float*)p;           p += (size_t)NN * sizeof(float);
    int* rowptr = (int*)p;             p += (size_t)(NN + 4) * sizeof(int);
    int* col    = (int*)p;             p += (size_t)NE * sizeof(int);
    int2* ebuf  = (int2*)p;            p += (size_t)NE * sizeof(int2);
    int* bhist  = (int*)p;             p += (size_t)(NB + 4) * sizeof(int);
    int* bbase  = (int*)p;             p += (size_t)(NB + 4) * sizeof(int);
    int* bcur   = (int*)p;             p += (size_t)(NB + 4) * sizeof(int);
    int* gstart = (int*)p;             p += (size_t)(NG + 4) * sizeof(int);
    float* pooled = (float*)p;         p += (size_t)NG * DF * sizeof(float);
    float* part  = (float*)p;          p += (size_t)NG * PCH * DF * sizeof(float);

    const int* e_src = ei;
    const int* e_dst = ei + NE;

    // CSR build + graph bounds
    k_init<<<3, 256, 0, stream>>>(bhist, batch, gstart);
    k_bcount<<<NBLKA, 256, 0, stream>>>(e_dst, bhist);
    k_bscan<<<1, 512, 0, stream>>>(bhist, bbase, bcur);
    k_pairs<<<NBLKA, 256, 0, stream>>>(e_src, e_dst, bcur, ebuf);
    k_build<<<NB, 256, 0, stream>>>(ebuf, bbase, rowptr, dinv, col);

    // bf16 conversions
    k_prepw<<<dim3(8, 3), 256, 0, stream>>>(W1, W2, W3, Wb1, Wb2, Wb3);
    k_prepx<<<(NN * DF / 8 + 255) / 256, 256, 0, stream>>>(x, xb);

    int ggrid = (NN + 63) / 64;
    int agg_blocks = NN / 4;   // 1 wave per node, 4 waves/block

    // layer 1
    k_gemm<<<ggrid, 256, 0, stream>>>(xb, Wb1, dinv, fs8);
    k_agg<<<agg_blocks, 256, 0, stream>>>(fs8, rowptr, col, dinv, b1, ob);
    // layer 2
    k_gemm<<<ggrid, 256, 0, stream>>>(ob, Wb2, dinv, fs8);
    k_agg<<<agg_blocks, 256, 0, stream>>>(fs8, rowptr, col, dinv, b2, ob);
    // layer 3
    k_gemm<<<ggrid, 256, 0, stream>>>(ob, Wb3, dinv, fs8);
    k_agg<<<agg_blocks, 256, 0, stream>>>(fs8, rowptr, col, dinv, b3, ob);

    // pool + fc
    k_poolA<<<NG * PCH, 256, 0, stream>>>(ob, gstart, part);
    k_poolB<<<NG, 128, 0, stream>>>(part, gstart, pooled);
    k_fc<<<NG, 64, 0, stream>>>(pooled, Wfc, bfc, out);
}

// Round 13
// 374.655 us; speedup vs baseline: 2.8169x; 1.0412x over previous
//
#include <hip/hip_runtime.h>

#define NN 100000
#define NE 1600000
#define DF 128
#define DOUT 64
#define NG 128
#define NB 391      // ceil(NN/256) buckets of 256 nodes
#define EPB 8192    // edges per block in binning passes
#define NBLKA ((NE + EPB - 1) / EPB)  // 196
#define PCH 8       // pool chunks per graph

typedef short short8 __attribute__((ext_vector_type(8)));
typedef float floatx4 __attribute__((ext_vector_type(4)));
typedef float floatx2 __attribute__((ext_vector_type(2)));

__device__ __forceinline__ unsigned short f2bf(float f) {
    unsigned int b = __float_as_uint(f);
    unsigned int r = (b + 0x7fffu + ((b >> 16) & 1u)) >> 16;
    return (unsigned short)r;
}
__device__ __forceinline__ float bf2f_lo(unsigned int v) { return __uint_as_float(v << 16); }
__device__ __forceinline__ float bf2f_hi(unsigned int v) { return __uint_as_float(v & 0xffff0000u); }

// physical feature index p -> logical feature c.
// p = g*64 + lm*4 + u  (g:0..1, lm:0..15, u:0..3), c = (g*4+u)*16 + lm
__device__ __forceinline__ int phi(int p) {
    return (((p >> 6) << 2) + (p & 3)) * 16 + ((p >> 2) & 15);
}

// ---------------- CSR build: LDS-binned radix partition ----------------

__global__ void k_init(int* __restrict__ bhist, const int* __restrict__ batch,
                       int* __restrict__ gstart) {
    if (blockIdx.x < 2) {
        int i = blockIdx.x * 256 + threadIdx.x;
        if (i < NB) bhist[i] = 0;
    } else {
        int g = threadIdx.x;
        if (g > NG) return;
        int lo = 0, hi = NN;
        while (lo < hi) {
            int mid = (lo + hi) >> 1;
            if (batch[mid] < g) lo = mid + 1; else hi = mid;
        }
        gstart[g] = lo;
    }
}

__global__ __launch_bounds__(256) void k_bcount(const int* __restrict__ dst,
                                                int* __restrict__ bhist) {
    __shared__ int lh[NB];
    int t = threadIdx.x;
    for (int i = t; i < NB; i += 256) lh[i] = 0;
    __syncthreads();
    int e0 = blockIdx.x * EPB;
    int e1 = min(e0 + EPB, NE);
    for (int e = e0 + t; e < e1; e += 256) atomicAdd(&lh[dst[e] >> 8], 1);
    __syncthreads();
    for (int i = t; i < NB; i += 256) {
        int c = lh[i];
        if (c) atomicAdd(&bhist[i], c);
    }
}

__global__ __launch_bounds__(512) void k_bscan(const int* __restrict__ bhist,
                                               int* __restrict__ bbase,
                                               int* __restrict__ bcur) {
    __shared__ int sh[512];
    int t = threadIdx.x;
    int v = (t < NB) ? bhist[t] : 0;
    sh[t] = v;
    __syncthreads();
    for (int off = 1; off < 512; off <<= 1) {
        int a = (t >= off) ? sh[t - off] : 0;
        __syncthreads();
        sh[t] += a;
        __syncthreads();
    }
    if (t < NB) {
        bbase[t] = sh[t] - v;
        bcur[t] = sh[t] - v;
    }
    if (t == NB - 1) bbase[NB] = sh[t];
}

__global__ __launch_bounds__(256) void k_pairs(const int* __restrict__ src,
                                               const int* __restrict__ dst,
                                               int* __restrict__ bcur,
                                               int2* __restrict__ ebuf) {
    __shared__ int lh[NB];
    __shared__ int lbase[NB];
    int t = threadIdx.x;
    for (int i = t; i < NB; i += 256) lh[i] = 0;
    __syncthreads();
    int e0 = blockIdx.x * EPB;
    int e1 = min(e0 + EPB, NE);
    for (int e = e0 + t; e < e1; e += 256) atomicAdd(&lh[dst[e] >> 8], 1);
    __syncthreads();
    for (int i = t; i < NB; i += 256) {
        int c = lh[i];
        lbase[i] = c ? atomicAdd(&bcur[i], c) : 0;
    }
    __syncthreads();
    for (int i = t; i < NB; i += 256) lh[i] = 0;
    __syncthreads();
    for (int e = e0 + t; e < e1; e += 256) {
        int s = src[e], d = dst[e];
        int bk = d >> 8;
        int off = atomicAdd(&lh[bk], 1);
        ebuf[lbase[bk] + off] = make_int2(s, d);
    }
}

// col stores BYTE offsets (src*DF) for k_agg address math
__global__ __launch_bounds__(256) void k_build(const int2* __restrict__ ebuf,
                                               const int* __restrict__ bbase,
                                               int* __restrict__ rowptr,
                                               float* __restrict__ dinv,
                                               int* __restrict__ col) {
    __shared__ int deg[256];
    __shared__ int lst[256];
    int b = blockIdx.x, t = threadIdx.x;
    int n0 = b << 8;
    int node = n0 + t;
    deg[t] = 0;
    __syncthreads();
    int e0 = bbase[b], e1 = bbase[b + 1];
    for (int e = e0 + t; e < e1; e += 256) atomicAdd(&deg[ebuf[e].y - n0], 1);
    __syncthreads();
    int v = deg[t];
    lst[t] = v;
    __syncthreads();
    for (int off = 1; off < 256; off <<= 1) {
        int a = (t >= off) ? lst[t - off] : 0;
        __syncthreads();
        lst[t] += a;
        __syncthreads();
    }
    int mystart = e0 + lst[t] - v;
    if (node < NN) {
        rowptr[node] = mystart;
        dinv[node] = rsqrtf((float)(v + 1));  // +1 self-loop
    }
    if (b == NB - 1 && t == 255) rowptr[NN] = e1;
    lst[t] = mystart;
    __syncthreads();
    for (int e = e0 + t; e < e1; e += 256) {
        int2 pr = ebuf[e];
        int p = atomicAdd(&lst[pr.y - n0], 1);
        col[p] = pr.x * DF;
    }
}

// ---------------- bf16 conversions ----------------

__global__ __launch_bounds__(256) void k_prepw(const float* __restrict__ Wa,
                                               const float* __restrict__ Wbm,
                                               const float* __restrict__ Wc,
                                               unsigned short* __restrict__ Oa,
                                               unsigned short* __restrict__ Ob,
                                               unsigned short* __restrict__ Oc) {
    const float* W = (blockIdx.y == 0) ? Wa : (blockIdx.y == 1) ? Wbm : Wc;
    unsigned short* O = (blockIdx.y == 0) ? Oa : (blockIdx.y == 1) ? Ob : Oc;
    int idx = blockIdx.x * 256 + threadIdx.x;
    if (idx >= 2048) return;
    int l = idx & 63;
    int s = (idx >> 6) & 3;
    int t = idx >> 8;
    int k0 = s * 32 + (l >> 4) * 8;
    int c = t * 16 + (l & 15);
    unsigned short o[8];
#pragma unroll
    for (int j = 0; j < 8; j++) o[j] = f2bf(W[phi(k0 + j) * DF + c]);
    *(short8*)&O[idx * 8] = *(short8*)o;
}

// x f32 -> bf16, permuted feature order (row-major)
__global__ __launch_bounds__(256) void k_prepx(const float* __restrict__ x,
                                               unsigned short* __restrict__ xb) {
    size_t i = ((size_t)blockIdx.x * 256 + threadIdx.x) * 8;
    if (i >= (size_t)NN * DF) return;
    size_t rb = i & ~(size_t)127;
    int p0 = (int)(i & 127);
    unsigned short o[8];
#pragma unroll
    for (int j = 0; j < 8; j++) o[j] = f2bf(x[rb + phi(p0 + j)]);
    *(short8*)&xb[i] = *(short8*)o;
}

// ---------------- per-layer compute ----------------

// output ONLY fp8 (row-major, 128 B/row) — self term also read from fs8 in k_agg
__global__ __launch_bounds__(256) void k_gemm(const unsigned short* __restrict__ X,
                                              const unsigned short* __restrict__ Wb,
                                              const float* __restrict__ dinv,
                                              unsigned char* __restrict__ fs8) {
    int t = threadIdx.x;
    int wave = t >> 6, l = t & 63;
    int r0 = blockIdx.x * 64 + wave * 16;
    int lm = l & 15, q = l >> 4;

    int arow = r0 + lm;
    if (arow >= NN) arow = NN - 1;
    const unsigned short* xrow = X + (size_t)arow * DF + q * 8;
    short8 af0 = *(const short8*)(xrow);
    short8 af1 = *(const short8*)(xrow + 32);
    short8 af2 = *(const short8*)(xrow + 64);
    short8 af3 = *(const short8*)(xrow + 96);

    int orow = r0 + q * 4;
    float dv[4];
#pragma unroll
    for (int j = 0; j < 4; j++) dv[j] = (orow + j < NN) ? dinv[orow + j] : 0.f;

    float res[4][8];
#pragma unroll
    for (int tt = 0; tt < 8; tt++) {
        floatx4 acc = {0.f, 0.f, 0.f, 0.f};
        const unsigned short* wp = Wb + ((size_t)(tt * 4) * 64 + l) * 8;
        acc = __builtin_amdgcn_mfma_f32_16x16x32_bf16(af0, *(const short8*)(wp), acc, 0, 0, 0);
        acc = __builtin_amdgcn_mfma_f32_16x16x32_bf16(af1, *(const short8*)(wp + 512), acc, 0, 0, 0);
        acc = __builtin_amdgcn_mfma_f32_16x16x32_bf16(af2, *(const short8*)(wp + 1024), acc, 0, 0, 0);
        acc = __builtin_amdgcn_mfma_f32_16x16x32_bf16(af3, *(const short8*)(wp + 1536), acc, 0, 0, 0);
#pragma unroll
        for (int j = 0; j < 4; j++) res[j][tt] = acc[j] * dv[j];
    }

#pragma unroll
    for (int g = 0; g < 2; g++) {
#pragma unroll
        for (int j = 0; j < 4; j++) {
            int r = orow + j;
            if (r >= NN) continue;
            unsigned int w8 = __builtin_amdgcn_cvt_pk_fp8_f32(res[j][g * 4 + 0], res[j][g * 4 + 1], 0, false);
            w8 = __builtin_amdgcn_cvt_pk_fp8_f32(res[j][g * 4 + 2], res[j][g * 4 + 3], w8, true);
            *(unsigned int*)&fs8[(size_t)r * DF + g * 64 + lm * 4] = w8;
        }
    }
}

// 1 wave per node; lane = (sub 0..3, fo 0..15). Degree-adaptive unroll:
// deg<=16: 4 gathers in flight; deg>16: 32-edge loop, 8 gathers (4KB/wave).
// Packed fp8 converts (2/instr) + float2 accumulators (v_pk_add_f32).
__global__ __launch_bounds__(256) void k_agg(const unsigned char* __restrict__ fs8,
                                             const int* __restrict__ colb,
                                             const int* __restrict__ rowptr,
                                             const float* __restrict__ dinv,
                                             const float* __restrict__ b,
                                             unsigned short* __restrict__ out) {
    int n = (int)((blockIdx.x * (size_t)blockDim.x + threadIdx.x) >> 6);
    int lane = threadIdx.x & 63;
    int sub = lane >> 4;       // edge slot within group of 4
    int fo = lane & 15;        // feature octet: physical features fo*8..fo*8+7
    int foff = fo * 8;

    int e0 = rowptr[n], e1 = rowptr[n + 1];
    int degn = e1 - e0;

    floatx2 acc0 = {0.f, 0.f}, acc1 = {0.f, 0.f}, acc2 = {0.f, 0.f}, acc3 = {0.f, 0.f};

    if (degn > 16) {
        for (int base = e0; base < e1; base += 32) {
            int idx[8], cb[8];
#pragma unroll
            for (int k = 0; k < 8; k++) {
                idx[k] = base + k * 4 + sub;
                cb[k] = colb[min(idx[k], e1 - 1)];
            }
            uint2 vv[8];
#pragma unroll
            for (int k = 0; k < 8; k++) vv[k] = *(const uint2*)&fs8[(size_t)cb[k] + foff];
#pragma unroll
            for (int k = 0; k < 8; k++) {
                if (idx[k] < e1) {
                    acc0 += __builtin_amdgcn_cvt_pk_f32_fp8(vv[k].x, false);
                    acc1 += __builtin_amdgcn_cvt_pk_f32_fp8(vv[k].x, true);
                    acc2 += __builtin_amdgcn_cvt_pk_f32_fp8(vv[k].y, false);
                    acc3 += __builtin_amdgcn_cvt_pk_f32_fp8(vv[k].y, true);
                }
            }
        }
    } else if (degn > 0) {
        int idx[4], cb[4];
#pragma unroll
        for (int k = 0; k < 4; k++) {
            idx[k] = e0 + k * 4 + sub;
            cb[k] = colb[min(idx[k], e1 - 1)];
        }
        uint2 vv[4];
#pragma unroll
        for (int k = 0; k < 4; k++) vv[k] = *(const uint2*)&fs8[(size_t)cb[k] + foff];
#pragma unroll
        for (int k = 0; k < 4; k++) {
            if (idx[k] < e1) {
                acc0 += __builtin_amdgcn_cvt_pk_f32_fp8(vv[k].x, false);
                acc1 += __builtin_amdgcn_cvt_pk_f32_fp8(vv[k].x, true);
                acc2 += __builtin_amdgcn_cvt_pk_f32_fp8(vv[k].y, false);
                acc3 += __builtin_amdgcn_cvt_pk_f32_fp8(vv[k].y, true);
            }
        }
    }

    float a[8] = {acc0.x, acc0.y, acc1.x, acc1.y, acc2.x, acc2.y, acc3.x, acc3.y};
#pragma unroll
    for (int j = 0; j < 8; j++) {
        a[j] += __shfl_xor(a[j], 16);
        a[j] += __shfl_xor(a[j], 32);
    }

    if (sub == 0) {
        uint2 sv = *(const uint2*)&fs8[(size_t)n * DF + foff];  // self-loop row (fp8)
        floatx2 s0 = __builtin_amdgcn_cvt_pk_f32_fp8(sv.x, false);
        floatx2 s1 = __builtin_amdgcn_cvt_pk_f32_fp8(sv.x, true);
        floatx2 s2 = __builtin_amdgcn_cvt_pk_f32_fp8(sv.y, false);
        floatx2 s3 = __builtin_amdgcn_cvt_pk_f32_fp8(sv.y, true);
        float sf[8] = {s0.x, s0.y, s1.x, s1.y, s2.x, s2.y, s3.x, s3.y};
        float dvn = dinv[n];
        float o[8];
#pragma unroll
        for (int j = 0; j < 8; j++)
            o[j] = fmaxf(dvn * (a[j] + sf[j]) + b[phi(foff + j)], 0.f);
        uint4 pk;
        pk.x = (unsigned int)f2bf(o[0]) | ((unsigned int)f2bf(o[1]) << 16);
        pk.y = (unsigned int)f2bf(o[2]) | ((unsigned int)f2bf(o[3]) << 16);
        pk.z = (unsigned int)f2bf(o[4]) | ((unsigned int)f2bf(o[5]) << 16);
        pk.w = (unsigned int)f2bf(o[6]) | ((unsigned int)f2bf(o[7]) << 16);
        *(uint4*)&out[(size_t)n * DF + foff] = pk;
    }
}

// ---------------- pooling + FC ----------------

__global__ __launch_bounds__(256) void k_poolA(const unsigned short* __restrict__ h,
                                               const int* __restrict__ gstart,
                                               float* __restrict__ part) {
    __shared__ float2 red[256];
    int g = blockIdx.x >> 3, c = blockIdx.x & 7;
    int s = gstart[g], e = gstart[g + 1];
    int len = e - s;
    int cs = s + (int)(((long long)len * c) >> 3);
    int ce = s + (int)(((long long)len * (c + 1)) >> 3);
    int t = threadIdx.x;
    int fp = t & 63;
    int rs = t >> 6;
    float2 acc = make_float2(0.f, 0.f);
    for (int n = cs + rs; n < ce; n += 4) {
        unsigned int v = *(const unsigned int*)&h[(size_t)n * DF + fp * 2];
        acc.x += bf2f_lo(v);
        acc.y += bf2f_hi(v);
    }
    red[t] = acc;
    __syncthreads();
    if (rs == 0) {
        float2 a0 = red[fp], a1 = red[fp + 64], a2 = red[fp + 128], a3 = red[fp + 192];
        float2 o;
        o.x = (a0.x + a1.x) + (a2.x + a3.x);
        o.y = (a0.y + a1.y) + (a2.y + a3.y);
        *(float2*)&part[(size_t)blockIdx.x * DF + fp * 2] = o;
    }
}

__global__ __launch_bounds__(128) void k_poolB(const float* __restrict__ part,
                                               const int* __restrict__ gstart,
                                               float* __restrict__ pooled) {
    int g = blockIdx.x;
    int f = threadIdx.x;
    float s = 0.f;
#pragma unroll
    for (int c = 0; c < PCH; c++) s += part[(size_t)(g * PCH + c) * DF + f];
    int cnt = gstart[g + 1] - gstart[g];
    pooled[g * DF + phi(f)] = s / (float)max(cnt, 1);
}

__global__ __launch_bounds__(64) void k_fc(const float* __restrict__ pooled,
                                           const float* __restrict__ Wfc,
                                           const float* __restrict__ bfc,
                                           float* __restrict__ out) {
    int g = blockIdx.x;
    int o = threadIdx.x;
    float acc = bfc[o];
    for (int k = 0; k < DF; k++) acc += pooled[g * DF + k] * Wfc[k * DOUT + o];
    out[g * DOUT + o] = acc;
}

// ---------------- launch ----------------

extern "C" void kernel_launch(void* const* d_in, const int* in_sizes, int n_in,
                              void* d_out, int out_size, void* d_ws, size_t ws_size,
                              hipStream_t stream) {
    const float* x     = (const float*)d_in[0];
    const int*   ei    = (const int*)d_in[1];
    const int*   batch = (const int*)d_in[2];
    const float* W1 = (const float*)d_in[3];
    const float* b1 = (const float*)d_in[4];
    const float* W2 = (const float*)d_in[5];
    const float* b2 = (const float*)d_in[6];
    const float* W3 = (const float*)d_in[7];
    const float* b3 = (const float*)d_in[8];
    const float* Wfc = (const float*)d_in[9];
    const float* bfc = (const float*)d_in[10];
    float* out = (float*)d_out;

    char* p = (char*)d_ws;
    unsigned short* xb = (unsigned short*)p;  p += (size_t)NN * DF * sizeof(short);
    unsigned short* ob = (unsigned short*)p;  p += (size_t)NN * DF * sizeof(short);
    unsigned char*  fs8 = (unsigned char*)p;  p += (size_t)NN * DF;
    unsigned short* Wb1 = (unsigned short*)p; p += 16384 * sizeof(short);
    unsigned short* Wb2 = (unsigned short*)p; p += 16384 * sizeof(short);
    unsigned short* Wb3 = (unsigned short*)p; p += 16384 * sizeof(short);
    float* dinv = (float*)p;           p += (size_t)NN * sizeof(float);
    int* rowptr = (int*)p;             p += (size_t)(NN + 4) * sizeof(int);
    int* col    = (int*)p;             p += (size_t)NE * sizeof(int);
    int2* ebuf  = (int2*)p;            p += (size_t)NE * sizeof(int2);
    int* bhist  = (int*)p;             p += (size_t)(NB + 4) * sizeof(int);
    int* bbase  = (int*)p;             p += (size_t)(NB + 4) * sizeof(int);
    int* bcur   = (int*)p;             p += (size_t)(NB + 4) * sizeof(int);
    int* gstart = (int*)p;             p += (size_t)(NG + 4) * sizeof(int);
    float* pooled = (float*)p;         p += (size_t)NG * DF * sizeof(float);
    float* part  = (float*)p;          p += (size_t)NG * PCH * DF * sizeof(float);

    const int* e_src = ei;
    const int* e_dst = ei + NE;

    // CSR build + graph bounds
    k_init<<<3, 256, 0, stream>>>(bhist, batch, gstart);
    k_bcount<<<NBLKA, 256, 0, stream>>>(e_dst, bhist);
    k_bscan<<<1, 512, 0, stream>>>(bhist, bbase, bcur);
    k_pairs<<<NBLKA, 256, 0, stream>>>(e_src, e_dst, bcur, ebuf);
    k_build<<<NB, 256, 0, stream>>>(ebuf, bbase, rowptr, dinv, col);

    // bf16 conversions
    k_prepw<<<dim3(8, 3), 256, 0, stream>>>(W1, W2, W3, Wb1, Wb2, Wb3);
    k_prepx<<<(NN * DF / 8 + 255) / 256, 256, 0, stream>>>(x, xb);

    int ggrid = (NN + 63) / 64;
    int agg_blocks = NN / 4;   // 1 wave per node, 4 waves/block

    // layer 1
    k_gemm<<<ggrid, 256, 0, stream>>>(xb, Wb1, dinv, fs8);
    k_agg<<<agg_blocks, 256, 0, stream>>>(fs8, col, rowptr, dinv, b1, ob);
    // layer 2
    k_gemm<<<ggrid, 256, 0, stream>>>(ob, Wb2, dinv, fs8);
    k_agg<<<agg_blocks, 256, 0, stream>>>(fs8, col, rowptr, dinv, b2, ob);
    // layer 3
    k_gemm<<<ggrid, 256, 0, stream>>>(ob, Wb3, dinv, fs8);
    k_agg<<<agg_blocks, 256, 0, stream>>>(fs8, col, rowptr, dinv, b3, ob);

    // pool + fc
    k_poolA<<<NG * PCH, 256, 0, stream>>>(ob, gstart, part);
    k_poolB<<<NG, 128, 0, stream>>>(part, gstart, pooled);
    k_fc<<<NG, 64, 0, stream>>>(pooled, Wfc, bfc, out);
}

// Round 15
// 372.003 us; speedup vs baseline: 2.8370x; 1.0071x over previous
//
#include <hip/hip_runtime.h>

#define NN 100000
#define NE 1600000
#define DF 128
#define DOUT 64
#define NG 128
#define NB 391      // ceil(NN/256) buckets of 256 nodes
#define EPB 8192    // edges per block in binning passes
#define NBLKA ((NE + EPB - 1) / EPB)  // 196
#define NBLKX 6250  // prepx blocks: NN*DF/8/256
#define PCH 8       // pool chunks per graph

typedef short short8 __attribute__((ext_vector_type(8)));
typedef float floatx4 __attribute__((ext_vector_type(4)));
typedef float floatx2 __attribute__((ext_vector_type(2)));

__device__ __forceinline__ unsigned short f2bf(float f) {
    unsigned int b = __float_as_uint(f);
    unsigned int r = (b + 0x7fffu + ((b >> 16) & 1u)) >> 16;
    return (unsigned short)r;
}
__device__ __forceinline__ float bf2f_lo(unsigned int v) { return __uint_as_float(v << 16); }
__device__ __forceinline__ float bf2f_hi(unsigned int v) { return __uint_as_float(v & 0xffff0000u); }

// physical feature index p -> logical feature c.
// p = g*64 + lm*4 + u  (g:0..1, lm:0..15, u:0..3), c = (g*4+u)*16 + lm
__device__ __forceinline__ int phi(int p) {
    return (((p >> 6) << 2) + (p & 3)) * 16 + ((p >> 2) & 15);
}

// ---------------- fused init: zero bhist + graph bounds + prepw (bf16 frags) ----------------

__global__ __launch_bounds__(256) void k_init(int* __restrict__ bhist,
                                              const int* __restrict__ batch,
                                              int* __restrict__ gstart,
                                              const float* __restrict__ W1,
                                              const float* __restrict__ W2,
                                              const float* __restrict__ W3,
                                              unsigned short* __restrict__ O1,
                                              unsigned short* __restrict__ O2,
                                              unsigned short* __restrict__ O3) {
    int blk = blockIdx.x;
    if (blk < 2) {
        int i = blk * 256 + threadIdx.x;
        if (i < NB) bhist[i] = 0;
    } else if (blk == 2) {
        int g = threadIdx.x;
        if (g > NG) return;
        int lo = 0, hi = NN;
        while (lo < hi) {
            int mid = (lo + hi) >> 1;
            if (batch[mid] < g) lo = mid + 1; else hi = mid;
        }
        gstart[g] = lo;
    } else {
        int bb = blk - 3;
        const float* W = (bb >= 16) ? W3 : (bb >= 8) ? W2 : W1;
        unsigned short* O = (bb >= 16) ? O3 : (bb >= 8) ? O2 : O1;
        int idx = (bb & 7) * 256 + threadIdx.x;
        int l = idx & 63;
        int s = (idx >> 6) & 3;
        int tt = idx >> 8;
        int k0 = s * 32 + (l >> 4) * 8;
        int c = tt * 16 + (l & 15);
        unsigned short o[8];
#pragma unroll
        for (int j = 0; j < 8; j++) o[j] = f2bf(W[phi(k0 + j) * DF + c]);
        *(short8*)&O[idx * 8] = *(short8*)o;
    }
}

// ---------------- fused: per-block dst histogram + prepx (x f32 -> bf16 permuted) ----------------

__global__ __launch_bounds__(256) void k_pre(const int* __restrict__ dst,
                                             int* __restrict__ bhist,
                                             const float* __restrict__ x,
                                             unsigned short* __restrict__ xb) {
    __shared__ int lh[NB];
    int t = threadIdx.x;
    if (blockIdx.x < NBLKA) {
        for (int i = t; i < NB; i += 256) lh[i] = 0;
        __syncthreads();
        int e0 = blockIdx.x * EPB;
        int e1 = min(e0 + EPB, NE);
        for (int e = e0 + t; e < e1; e += 256) atomicAdd(&lh[dst[e] >> 8], 1);
        __syncthreads();
        for (int i = t; i < NB; i += 256) {
            int c = lh[i];
            if (c) atomicAdd(&bhist[i], c);
        }
    } else {
        size_t i = ((size_t)(blockIdx.x - NBLKA) * 256 + t) * 8;
        size_t rb = i & ~(size_t)127;
        int p0 = (int)(i & 127);
        unsigned short o[8];
#pragma unroll
        for (int j = 0; j < 8; j++) o[j] = f2bf(x[rb + phi(p0 + j)]);
        *(short8*)&xb[i] = *(short8*)o;
    }
}

__global__ __launch_bounds__(512) void k_bscan(const int* __restrict__ bhist,
                                               int* __restrict__ bbase,
                                               int* __restrict__ bcur) {
    __shared__ int sh[512];
    int t = threadIdx.x;
    int v = (t < NB) ? bhist[t] : 0;
    sh[t] = v;
    __syncthreads();
    for (int off = 1; off < 512; off <<= 1) {
        int a = (t >= off) ? sh[t - off] : 0;
        __syncthreads();
        sh[t] += a;
        __syncthreads();
    }
    if (t < NB) {
        bbase[t] = sh[t] - v;
        bcur[t] = sh[t] - v;
    }
    if (t == NB - 1) bbase[NB] = sh[t];
}

__global__ __launch_bounds__(256) void k_pairs(const int* __restrict__ src,
                                               const int* __restrict__ dst,
                                               int* __restrict__ bcur,
                                               int2* __restrict__ ebuf) {
    __shared__ int lh[NB];
    __shared__ int lbase[NB];
    int t = threadIdx.x;
    for (int i = t; i < NB; i += 256) lh[i] = 0;
    __syncthreads();
    int e0 = blockIdx.x * EPB;
    int e1 = min(e0 + EPB, NE);
    for (int e = e0 + t; e < e1; e += 256) atomicAdd(&lh[dst[e] >> 8], 1);
    __syncthreads();
    for (int i = t; i < NB; i += 256) {
        int c = lh[i];
        lbase[i] = c ? atomicAdd(&bcur[i], c) : 0;
    }
    __syncthreads();
    for (int i = t; i < NB; i += 256) lh[i] = 0;
    __syncthreads();
    for (int e = e0 + t; e < e1; e += 256) {
        int s = src[e], d = dst[e];
        int bk = d >> 8;
        int off = atomicAdd(&lh[bk], 1);
        ebuf[lbase[bk] + off] = make_int2(s, d);
    }
}

// col stores BYTE offsets (src*DF) for k_agg fp8 table (128 B rows)
__global__ __launch_bounds__(256) void k_build(const int2* __restrict__ ebuf,
                                               const int* __restrict__ bbase,
                                               int* __restrict__ rowptr,
                                               float* __restrict__ dinv,
                                               int* __restrict__ col) {
    __shared__ int deg[256];
    __shared__ int lst[256];
    int b = blockIdx.x, t = threadIdx.x;
    int n0 = b << 8;
    int node = n0 + t;
    deg[t] = 0;
    __syncthreads();
    int e0 = bbase[b], e1 = bbase[b + 1];
    for (int e = e0 + t; e < e1; e += 256) atomicAdd(&deg[ebuf[e].y - n0], 1);
    __syncthreads();
    int v = deg[t];
    lst[t] = v;
    __syncthreads();
    for (int off = 1; off < 256; off <<= 1) {
        int a = (t >= off) ? lst[t - off] : 0;
        __syncthreads();
        lst[t] += a;
        __syncthreads();
    }
    int mystart = e0 + lst[t] - v;
    if (node < NN) {
        rowptr[node] = mystart;
        dinv[node] = rsqrtf((float)(v + 1));  // +1 self-loop
    }
    if (b == NB - 1 && t == 255) rowptr[NN] = e1;
    lst[t] = mystart;
    __syncthreads();
    for (int e = e0 + t; e < e1; e += 256) {
        int2 pr = ebuf[e];
        int p = atomicAdd(&lst[pr.y - n0], 1);
        col[p] = pr.x * DF;
    }
}

// ---------------- per-layer compute ----------------

// fs8[r] = fp8( dinv[r] * X[r] @ W ), bf16 MFMA (weights stay bf16 for precision)
__global__ __launch_bounds__(256) void k_gemm(const unsigned short* __restrict__ X,
                                              const unsigned short* __restrict__ Wb,
                                              const float* __restrict__ dinv,
                                              unsigned char* __restrict__ fs8) {
    int t = threadIdx.x;
    int wave = t >> 6, l = t & 63;
    int r0 = blockIdx.x * 64 + wave * 16;
    int lm = l & 15, q = l >> 4;

    int arow = r0 + lm;
    if (arow >= NN) arow = NN - 1;
    const unsigned short* xrow = X + (size_t)arow * DF + q * 8;
    short8 af0 = *(const short8*)(xrow);
    short8 af1 = *(const short8*)(xrow + 32);
    short8 af2 = *(const short8*)(xrow + 64);
    short8 af3 = *(const short8*)(xrow + 96);

    int orow = r0 + q * 4;
    float dv[4];
#pragma unroll
    for (int j = 0; j < 4; j++) dv[j] = (orow + j < NN) ? dinv[orow + j] : 0.f;

    float res[4][8];
#pragma unroll
    for (int tt = 0; tt < 8; tt++) {
        floatx4 acc = {0.f, 0.f, 0.f, 0.f};
        const unsigned short* wp = Wb + ((size_t)(tt * 4) * 64 + l) * 8;
        acc = __builtin_amdgcn_mfma_f32_16x16x32_bf16(af0, *(const short8*)(wp), acc, 0, 0, 0);
        acc = __builtin_amdgcn_mfma_f32_16x16x32_bf16(af1, *(const short8*)(wp + 512), acc, 0, 0, 0);
        acc = __builtin_amdgcn_mfma_f32_16x16x32_bf16(af2, *(const short8*)(wp + 1024), acc, 0, 0, 0);
        acc = __builtin_amdgcn_mfma_f32_16x16x32_bf16(af3, *(const short8*)(wp + 1536), acc, 0, 0, 0);
#pragma unroll
        for (int j = 0; j < 4; j++) res[j][tt] = acc[j] * dv[j];
    }

#pragma unroll
    for (int g = 0; g < 2; g++) {
#pragma unroll
        for (int j = 0; j < 4; j++) {
            int r = orow + j;
            if (r >= NN) continue;
            unsigned int w8 = __builtin_amdgcn_cvt_pk_fp8_f32(res[j][g * 4 + 0], res[j][g * 4 + 1], 0, false);
            w8 = __builtin_amdgcn_cvt_pk_fp8_f32(res[j][g * 4 + 2], res[j][g * 4 + 3], w8, true);
            *(unsigned int*)&fs8[(size_t)r * DF + g * 64 + lm * 4] = w8;
        }
    }
}

// 1 wave per node; lane = (sub 0..3, fo 0..15). Degree-adaptive unroll (4KB/wave MLP).
// fp8 gathers + packed converts; writes bf16 activations.
__global__ __launch_bounds__(256) void k_agg(const unsigned char* __restrict__ fs8,
                                             const int* __restrict__ colb,
                                             const int* __restrict__ rowptr,
                                             const float* __restrict__ dinv,
                                             const float* __restrict__ b,
                                             unsigned short* __restrict__ out) {
    int n = (int)((blockIdx.x * (size_t)blockDim.x + threadIdx.x) >> 6);
    int lane = threadIdx.x & 63;
    int sub = lane >> 4;
    int fo = lane & 15;
    int foff = fo * 8;

    int e0 = rowptr[n], e1 = rowptr[n + 1];
    int degn = e1 - e0;

    floatx2 acc0 = {0.f, 0.f}, acc1 = {0.f, 0.f}, acc2 = {0.f, 0.f}, acc3 = {0.f, 0.f};

    if (degn > 16) {
        for (int base = e0; base < e1; base += 32) {
            int idx[8], cb[8];
#pragma unroll
            for (int k = 0; k < 8; k++) {
                idx[k] = base + k * 4 + sub;
                cb[k] = colb[min(idx[k], e1 - 1)];
            }
            uint2 vv[8];
#pragma unroll
            for (int k = 0; k < 8; k++) vv[k] = *(const uint2*)&fs8[(size_t)cb[k] + foff];
#pragma unroll
            for (int k = 0; k < 8; k++) {
                if (idx[k] < e1) {
                    acc0 += __builtin_amdgcn_cvt_pk_f32_fp8(vv[k].x, false);
                    acc1 += __builtin_amdgcn_cvt_pk_f32_fp8(vv[k].x, true);
                    acc2 += __builtin_amdgcn_cvt_pk_f32_fp8(vv[k].y, false);
                    acc3 += __builtin_amdgcn_cvt_pk_f32_fp8(vv[k].y, true);
                }
            }
        }
    } else if (degn > 0) {
        int idx[4], cb[4];
#pragma unroll
        for (int k = 0; k < 4; k++) {
            idx[k] = e0 + k * 4 + sub;
            cb[k] = colb[min(idx[k], e1 - 1)];
        }
        uint2 vv[4];
#pragma unroll
        for (int k = 0; k < 4; k++) vv[k] = *(const uint2*)&fs8[(size_t)cb[k] + foff];
#pragma unroll
        for (int k = 0; k < 4; k++) {
            if (idx[k] < e1) {
                acc0 += __builtin_amdgcn_cvt_pk_f32_fp8(vv[k].x, false);
                acc1 += __builtin_amdgcn_cvt_pk_f32_fp8(vv[k].x, true);
                acc2 += __builtin_amdgcn_cvt_pk_f32_fp8(vv[k].y, false);
                acc3 += __builtin_amdgcn_cvt_pk_f32_fp8(vv[k].y, true);
            }
        }
    }

    float a[8] = {acc0.x, acc0.y, acc1.x, acc1.y, acc2.x, acc2.y, acc3.x, acc3.y};
#pragma unroll
    for (int j = 0; j < 8; j++) {
        a[j] += __shfl_xor(a[j], 16);
        a[j] += __shfl_xor(a[j], 32);
    }

    if (sub == 0) {
        uint2 sv = *(const uint2*)&fs8[(size_t)n * DF + foff];  // self-loop row (fp8)
        floatx2 s0 = __builtin_amdgcn_cvt_pk_f32_fp8(sv.x, false);
        floatx2 s1 = __builtin_amdgcn_cvt_pk_f32_fp8(sv.x, true);
        floatx2 s2 = __builtin_amdgcn_cvt_pk_f32_fp8(sv.y, false);
        floatx2 s3 = __builtin_amdgcn_cvt_pk_f32_fp8(sv.y, true);
        float sf[8] = {s0.x, s0.y, s1.x, s1.y, s2.x, s2.y, s3.x, s3.y};
        float dvn = dinv[n];
        float o[8];
#pragma unroll
        for (int j = 0; j < 8; j++)
            o[j] = fmaxf(dvn * (a[j] + sf[j]) + b[phi(foff + j)], 0.f);
        uint4 pk;
        pk.x = (unsigned int)f2bf(o[0]) | ((unsigned int)f2bf(o[1]) << 16);
        pk.y = (unsigned int)f2bf(o[2]) | ((unsigned int)f2bf(o[3]) << 16);
        pk.z = (unsigned int)f2bf(o[4]) | ((unsigned int)f2bf(o[5]) << 16);
        pk.w = (unsigned int)f2bf(o[6]) | ((unsigned int)f2bf(o[7]) << 16);
        *(uint4*)&out[(size_t)n * DF + foff] = pk;
    }
}

// ---------------- pooling + FC ----------------

__global__ __launch_bounds__(256) void k_poolA(const unsigned short* __restrict__ h,
                                               const int* __restrict__ gstart,
                                               float* __restrict__ part) {
    __shared__ float2 red[256];
    int g = blockIdx.x >> 3, c = blockIdx.x & 7;
    int s = gstart[g], e = gstart[g + 1];
    int len = e - s;
    int cs = s + (int)(((long long)len * c) >> 3);
    int ce = s + (int)(((long long)len * (c + 1)) >> 3);
    int t = threadIdx.x;
    int fp = t & 63;
    int rs = t >> 6;
    float2 acc = make_float2(0.f, 0.f);
    for (int n = cs + rs; n < ce; n += 4) {
        unsigned int v = *(const unsigned int*)&h[(size_t)n * DF + fp * 2];
        acc.x += bf2f_lo(v);
        acc.y += bf2f_hi(v);
    }
    red[t] = acc;
    __syncthreads();
    if (rs == 0) {
        float2 a0 = red[fp], a1 = red[fp + 64], a2 = red[fp + 128], a3 = red[fp + 192];
        float2 o;
        o.x = (a0.x + a1.x) + (a2.x + a3.x);
        o.y = (a0.y + a1.y) + (a2.y + a3.y);
        *(float2*)&part[(size_t)blockIdx.x * DF + fp * 2] = o;
    }
}

// phase B + FC fused: reduce partials -> pooled (LDS, un-permuted) -> FC
__global__ __launch_bounds__(128) void k_poolfc(const float* __restrict__ part,
                                                const int* __restrict__ gstart,
                                                const float* __restrict__ Wfc,
                                                const float* __restrict__ bfc,
                                                float* __restrict__ out) {
    __shared__ float pl[DF];
    int g = blockIdx.x;
    int f = threadIdx.x;
    float s = 0.f;
#pragma unroll
    for (int c = 0; c < PCH; c++) s += part[(size_t)(g * PCH + c) * DF + f];
    int cnt = gstart[g + 1] - gstart[g];
    pl[phi(f)] = s / (float)max(cnt, 1);
    __syncthreads();
    if (f < DOUT) {
        float acc = bfc[f];
        for (int k = 0; k < DF; k++) acc += pl[k] * Wfc[k * DOUT + f];
        out[g * DOUT + f] = acc;
    }
}

// ---------------- launch ----------------

extern "C" void kernel_launch(void* const* d_in, const int* in_sizes, int n_in,
                              void* d_out, int out_size, void* d_ws, size_t ws_size,
                              hipStream_t stream) {
    const float* x     = (const float*)d_in[0];
    const int*   ei    = (const int*)d_in[1];
    const int*   batch = (const int*)d_in[2];
    const float* W1 = (const float*)d_in[3];
    const float* b1 = (const float*)d_in[4];
    const float* W2 = (const float*)d_in[5];
    const float* b2 = (const float*)d_in[6];
    const float* W3 = (const float*)d_in[7];
    const float* b3 = (const float*)d_in[8];
    const float* Wfc = (const float*)d_in[9];
    const float* bfc = (const float*)d_in[10];
    float* out = (float*)d_out;

    char* p = (char*)d_ws;
    unsigned short* xb = (unsigned short*)p;  p += (size_t)NN * DF * sizeof(short);
    unsigned short* ob = (unsigned short*)p;  p += (size_t)NN * DF * sizeof(short);
    unsigned char*  fs8 = (unsigned char*)p;  p += (size_t)NN * DF;
    unsigned short* Wb1 = (unsigned short*)p; p += 16384 * sizeof(short);
    unsigned short* Wb2 = (unsigned short*)p; p += 16384 * sizeof(short);
    unsigned short* Wb3 = (unsigned short*)p; p += 16384 * sizeof(short);
    float* dinv = (float*)p;           p += (size_t)NN * sizeof(float);
    int* rowptr = (int*)p;             p += (size_t)(NN + 4) * sizeof(int);
    int* col    = (int*)p;             p += (size_t)NE * sizeof(int);
    int2* ebuf  = (int2*)p;            p += (size_t)NE * sizeof(int2);
    int* bhist  = (int*)p;             p += (size_t)(NB + 4) * sizeof(int);
    int* bbase  = (int*)p;             p += (size_t)(NB + 4) * sizeof(int);
    int* bcur   = (int*)p;             p += (size_t)(NB + 4) * sizeof(int);
    int* gstart = (int*)p;             p += (size_t)(NG + 4) * sizeof(int);
    float* part = (float*)p;           p += (size_t)NG * PCH * DF * sizeof(float);

    const int* e_src = ei;
    const int* e_dst = ei + NE;

    // init (zero bhist + bounds + 3x bf16 prepw) ; binning + prepx fused
    k_init<<<27, 256, 0, stream>>>(bhist, batch, gstart, W1, W2, W3, Wb1, Wb2, Wb3);
    k_pre<<<NBLKA + NBLKX, 256, 0, stream>>>(e_dst, bhist, x, xb);
    k_bscan<<<1, 512, 0, stream>>>(bhist, bbase, bcur);
    k_pairs<<<NBLKA, 256, 0, stream>>>(e_src, e_dst, bcur, ebuf);
    k_build<<<NB, 256, 0, stream>>>(ebuf, bbase, rowptr, dinv, col);

    int ggrid = (NN + 63) / 64;
    int agg_blocks = NN / 4;

    // layer 1
    k_gemm<<<ggrid, 256, 0, stream>>>(xb, Wb1, dinv, fs8);
    k_agg<<<agg_blocks, 256, 0, stream>>>(fs8, col, rowptr, dinv, b1, ob);
    // layer 2
    k_gemm<<<ggrid, 256, 0, stream>>>(ob, Wb2, dinv, fs8);
    k_agg<<<agg_blocks, 256, 0, stream>>>(fs8, col, rowptr, dinv, b2, ob);
    // layer 3
    k_gemm<<<ggrid, 256, 0, stream>>>(ob, Wb3, dinv, fs8);
    k_agg<<<agg_blocks, 256, 0, stream>>>(fs8, col, rowptr, dinv, b3, ob);

    // pool + fc
    k_poolA<<<NG * PCH, 256, 0, stream>>>(ob, gstart, part);
    k_poolfc<<<NG, 128, 0, stream>>>(part, gstart, Wfc, bfc, out);
}